// Round 1
// baseline (4502.378 us; speedup 1.0000x reference)
//
#include <hip/hip_runtime.h>
#include <math.h>

// Shapes (fixed per reference setup_inputs):
#define BB 32
#define SFULL 513
#define TT 512
#define DD 1024
#define KK 256
#define VV 256
#define HH 2048
#define OO 256

// ---------------------------------------------------------------------------
// Generic tiled GEMM: C[m][n] = sum_k A[m][k] * B[n][k]   (A * B^T)
// 64x64 tile, BK=16, 256 threads, 4x4 micro-tile per thread.
// Batch via blockIdx.z with element strides. Accumulation in CT.
// All dims assumed divisible (M%64==0, N%64==0, K%16==0) — true for all uses.
// ---------------------------------------------------------------------------
template <typename AT, typename BT, typename CT>
__global__ __launch_bounds__(256) void gemm_abt(
    const AT* __restrict__ A, long long aBatch, int aPitch,
    const BT* __restrict__ Bm, long long bBatch, int bPitch,
    CT* __restrict__ C, long long cBatch, int cPitch, int Kd) {
  const int bz = blockIdx.z;
  A  += (size_t)bz * aBatch;
  Bm += (size_t)bz * bBatch;
  C  += (size_t)bz * cBatch;
  const int m0 = blockIdx.y * 64;
  const int n0 = blockIdx.x * 64;
  const int tid = threadIdx.x;
  const int tx = tid & 15;        // 0..15 -> n
  const int ty = tid >> 4;        // 0..15 -> m
  const int rl = tid >> 2;        // 0..63 row for loads
  const int kq = tid & 3;         // 0..3  k-quad for loads

  __shared__ AT As[16][65];
  __shared__ BT Bs[16][65];

  CT acc[4][4];
#pragma unroll
  for (int i = 0; i < 4; i++)
#pragma unroll
    for (int j = 0; j < 4; j++) acc[i][j] = (CT)0;

  for (int kk = 0; kk < Kd; kk += 16) {
    const AT* ap = A + (size_t)(m0 + rl) * aPitch + kk + kq * 4;
    const BT* bp = Bm + (size_t)(n0 + rl) * bPitch + kk + kq * 4;
#pragma unroll
    for (int i = 0; i < 4; i++) As[kq * 4 + i][rl] = ap[i];
#pragma unroll
    for (int i = 0; i < 4; i++) Bs[kq * 4 + i][rl] = bp[i];
    __syncthreads();
#pragma unroll
    for (int k = 0; k < 16; k++) {
      CT a[4], b[4];
#pragma unroll
      for (int i = 0; i < 4; i++) a[i] = (CT)As[k][ty * 4 + i];
#pragma unroll
      for (int j = 0; j < 4; j++) b[j] = (CT)Bs[k][tx * 4 + j];
#pragma unroll
      for (int i = 0; i < 4; i++)
#pragma unroll
        for (int j = 0; j < 4; j++) acc[i][j] += a[i] * b[j];
    }
    __syncthreads();
  }

#pragma unroll
  for (int i = 0; i < 4; i++) {
    CT* cp = C + (size_t)(m0 + ty * 4 + i) * cPitch + n0 + tx * 4;
#pragma unroll
    for (int j = 0; j < 4; j++) cp[j] = acc[i][j];
  }
}

// ---------------------------------------------------------------------------
// xQ = x[:, 512, :] @ W_Q^T   (fp32). One block per batch, 256 thr (4 waves),
// wave-per-output-column with lane-parallel K and shuffle reduce.
// Writes to ws copy and to d_out[40960..].
// ---------------------------------------------------------------------------
__global__ __launch_bounds__(256) void xq_kernel(const float* __restrict__ x,
                                                 const float* __restrict__ W_Q,
                                                 float* __restrict__ xQws,
                                                 float* __restrict__ outp) {
  const int b = blockIdx.x;
  const int tid = threadIdx.x;
  const int w = tid >> 6, lane = tid & 63;
  const float* xr = x + ((size_t)b * SFULL + TT) * DD;
  for (int n = w; n < KK; n += 4) {
    const float* wq = W_Q + (size_t)n * DD;
    float s = 0.f;
    for (int k = lane; k < DD; k += 64) s += wq[k] * xr[k];
#pragma unroll
    for (int off = 32; off; off >>= 1) s += __shfl_down(s, off);
    if (lane == 0) {
      xQws[b * KK + n] = s;
      outp[BB * OO + BB * DD + b * KK + n] = s;  // third output region
    }
  }
}

// ---------------------------------------------------------------------------
// Sequential winner-take-all scan. One block per batch (32 blocks, 1024 thr).
// Per step t: logits[h] = last[h]<0 ? L0t[b,t,h] : Gram[b,t,last[h]];
// argmax (first-index tie-break), last[winner]=t. Dumps last[] at the end.
// ---------------------------------------------------------------------------
__global__ __launch_bounds__(1024) void scan_kernel(const double* __restrict__ L0t,
                                                    const double* __restrict__ Gram,
                                                    int* __restrict__ lastmap) {
  const int b = blockIdx.x;
  const int tid = threadIdx.x;
  __shared__ int last[HH];
  __shared__ double rv[16];
  __shared__ int ri[16];
  last[tid] = -1;
  last[tid + 1024] = -1;
  __syncthreads();

  const double* L0b = L0t + (size_t)b * TT * HH;
  const double* Gb = Gram + (size_t)b * TT * TT;

  for (int t = 0; t < TT; t++) {
    const double* lrow = L0b + (size_t)t * HH;
    const double* grow = Gb + (size_t)t * TT;
    int l1 = last[tid];
    int l2 = last[tid + 1024];
    double v1 = (l1 < 0) ? lrow[tid] : grow[l1];
    double v2 = (l2 < 0) ? lrow[tid + 1024] : grow[l2];
    double v;
    int idx;
    if (v2 > v1) { v = v2; idx = tid + 1024; }
    else { v = v1; idx = tid; }  // tie -> smaller index
#pragma unroll
    for (int off = 32; off; off >>= 1) {
      double ov = __shfl_down(v, off);
      int oi = __shfl_down(idx, off);
      if (ov > v || (ov == v && oi < idx)) { v = ov; idx = oi; }
    }
    if ((tid & 63) == 0) { rv[tid >> 6] = v; ri[tid >> 6] = idx; }
    __syncthreads();
    if (tid < 64) {
      double vv = (tid < 16) ? rv[tid] : -INFINITY;
      int ii = (tid < 16) ? ri[tid] : 0x7fffffff;
#pragma unroll
      for (int off = 8; off; off >>= 1) {
        double ov = __shfl_down(vv, off);
        int oi = __shfl_down(ii, off);
        if (ov > vv || (ov == vv && oi < ii)) { vv = ov; ii = oi; }
      }
      if (tid == 0) last[ii] = t;
    }
    __syncthreads();
  }
  lastmap[b * HH + tid] = last[tid];
  lastmap[b * HH + tid + 1024] = last[tid + 1024];
}

// ---------------------------------------------------------------------------
// Epilogue stage 1: q-logits, softmax -> hv; emit hvm (masked hv for
// untouched rows) and wgt[s] (hv of the row whose final content is step s).
// One block per batch, 1024 threads (16 waves).
// ---------------------------------------------------------------------------
__global__ __launch_bounds__(1024) void epi1_kernel(const float* __restrict__ W_hi0,
                                                    const double* __restrict__ xK64,
                                                    const float* __restrict__ xQws,
                                                    const int* __restrict__ lastmap,
                                                    float* __restrict__ hvmg,
                                                    float* __restrict__ wgtg) {
  const int b = blockIdx.x;
  const int tid = threadIdx.x;
  const int w = tid >> 6, lane = tid & 63;
  __shared__ float xq[KK];
  __shared__ float ql[HH];
  __shared__ float red[16];
  __shared__ float redsum[16];
  if (tid < KK) xq[tid] = xQws[b * KK + tid];
  if (tid < TT) wgtg[b * TT + tid] = 0.f;
  __syncthreads();

  for (int h = w; h < HH; h += 16) {
    int li = lastmap[b * HH + h];
    float s = 0.f;
    if (li < 0) {
      const float* p = W_hi0 + ((size_t)b * HH + h) * KK;
      for (int k = lane; k < KK; k += 64) s += p[k] * xq[k];
    } else {
      const double* p = xK64 + ((size_t)b * TT + li) * KK;
      for (int k = lane; k < KK; k += 64) s += (float)p[k] * xq[k];
    }
#pragma unroll
    for (int off = 32; off; off >>= 1) s += __shfl_down(s, off);
    if (lane == 0) ql[h] = s;
  }
  __syncthreads();

  // softmax over 2048
  float lm = fmaxf(ql[tid], ql[tid + 1024]);
#pragma unroll
  for (int off = 32; off; off >>= 1) lm = fmaxf(lm, __shfl_down(lm, off));
  if (lane == 0) red[w] = lm;
  __syncthreads();
  if (tid == 0) {
    float m = red[0];
    for (int i = 1; i < 16; i++) m = fmaxf(m, red[i]);
    red[0] = m;
  }
  __syncthreads();
  const float mx = red[0];
  float e1 = expf(ql[tid] - mx);
  float e2 = expf(ql[tid + 1024] - mx);
  float ls = e1 + e2;
#pragma unroll
  for (int off = 32; off; off >>= 1) ls += __shfl_down(ls, off);
  if (lane == 0) redsum[w] = ls;
  __syncthreads();
  if (tid == 0) {
    float s = 0.f;
    for (int i = 0; i < 16; i++) s += redsum[i];
    redsum[0] = s;
  }
  __syncthreads();
  const float inv = 1.f / redsum[0];
  const float hv1 = e1 * inv, hv2 = e2 * inv;
  const int li1 = lastmap[b * HH + tid];
  const int li2 = lastmap[b * HH + tid + 1024];
  hvmg[b * HH + tid] = (li1 < 0) ? hv1 : 0.f;
  hvmg[b * HH + tid + 1024] = (li2 < 0) ? hv2 : 0.f;
  if (li1 >= 0) wgtg[b * TT + li1] = hv1;  // last is injective: no races
  if (li2 >= 0) wgtg[b * TT + li2] = hv2;
}

// ---------------------------------------------------------------------------
// Epilogue stage 2: reinst_context[b,d] = sum_h hvm[h]*W_reinst0[b,h,d]
//                                       + sum_s wgt[s]*ctx[b,s,d]
// Grid (4, 32) x 256 threads: block handles 256 of 1024 d's for one batch.
// ---------------------------------------------------------------------------
__global__ __launch_bounds__(256) void epi2_kernel(const float* __restrict__ W_reinst0,
                                                   const float* __restrict__ x,
                                                   const float* __restrict__ hvmg,
                                                   const float* __restrict__ wgtg,
                                                   float* __restrict__ outp) {
  const int b = blockIdx.y;
  const int tid = threadIdx.x;
  const int d = blockIdx.x * 256 + tid;
  __shared__ float hvm[HH];
  __shared__ float wgt[TT];
  for (int i = tid; i < HH; i += 256) hvm[i] = hvmg[b * HH + i];
  for (int i = tid; i < TT; i += 256) wgt[i] = wgtg[b * TT + i];
  __syncthreads();
  float acc = 0.f;
#pragma unroll 4
  for (int h = 0; h < HH; h++) {
    float hm = hvm[h];
    if (hm != 0.f) acc += hm * W_reinst0[((size_t)b * HH + h) * DD + d];
  }
#pragma unroll 4
  for (int s = 0; s < TT; s++) {
    float wv = wgt[s];
    if (wv != 0.f) acc += wv * x[((size_t)b * SFULL + s) * DD + d];
  }
  outp[BB * OO + b * DD + d] = acc;  // second output region
}

// ---------------------------------------------------------------------------
// Epilogue stage 3: mhn_out then out = mhn_out @ W_proj^T.
// One block per batch, 1024 threads (16 waves).
// ---------------------------------------------------------------------------
__global__ __launch_bounds__(1024) void epi3_kernel(const float* __restrict__ W_oh0,
                                                    const float* __restrict__ xVws,
                                                    const float* __restrict__ W_proj,
                                                    const float* __restrict__ hvmg,
                                                    const float* __restrict__ wgtg,
                                                    float* __restrict__ outp) {
  const int b = blockIdx.x;
  const int tid = threadIdx.x;
  const int w = tid >> 6, lane = tid & 63;
  __shared__ float hvm[HH];
  __shared__ float wgt[TT];
  __shared__ float mhn[VV];
  for (int i = tid; i < HH; i += 1024) hvm[i] = hvmg[b * HH + i];
  if (tid < TT) wgt[tid] = wgtg[b * TT + tid];
  __syncthreads();

  // term 1: untouched columns of W_oh0
  for (int v = w; v < VV; v += 16) {
    const float* p = W_oh0 + ((size_t)b * VV + v) * HH;
    float s = 0.f;
    for (int h = lane; h < HH; h += 64) s += hvm[h] * p[h];
#pragma unroll
    for (int off = 32; off; off >>= 1) s += __shfl_down(s, off);
    if (lane == 0) mhn[v] = s;
  }
  __syncthreads();
  // term 2: replaced columns = xv rows weighted by wgt
  if (tid < VV) {
    float s2 = 0.f;
#pragma unroll 4
    for (int s = 0; s < TT; s++) {
      float wv = wgt[s];
      if (wv != 0.f) s2 += wv * xVws[((size_t)b * TT + s) * VV + tid];
    }
    mhn[tid] += s2;
  }
  __syncthreads();
  // projection
  for (int o = w; o < OO; o += 16) {
    const float* p = W_proj + (size_t)o * VV;
    float s = 0.f;
    for (int v = lane; v < VV; v += 64) s += mhn[v] * p[v];
#pragma unroll
    for (int off = 32; off; off >>= 1) s += __shfl_down(s, off);
    if (lane == 0) outp[b * OO + o] = s;  // first output region
  }
}

// ---------------------------------------------------------------------------
extern "C" void kernel_launch(void* const* d_in, const int* in_sizes, int n_in,
                              void* d_out, int out_size, void* d_ws, size_t ws_size,
                              hipStream_t stream) {
  const float* x        = (const float*)d_in[0];
  const float* W_Q      = (const float*)d_in[1];
  const float* W_K      = (const float*)d_in[2];
  const float* W_V      = (const float*)d_in[3];
  const float* W_proj   = (const float*)d_in[4];
  const float* W_hi0    = (const float*)d_in[5];
  const float* W_oh0    = (const float*)d_in[6];
  const float* W_reinst0 = (const float*)d_in[7];
  float* outp = (float*)d_out;

  // workspace layout (bytes)
  char* ws = (char*)d_ws;
  double* xK64 = (double*)ws;                                  // 32*512*256*8   = 33,554,432
  double* Gram = (double*)(ws + 33554432);                     // 32*512*512*8   = 67,108,864
  double* L0t  = (double*)(ws + 100663296);                    // 32*512*2048*8  = 268,435,456
  float*  xVws = (float*)(ws + 369098752);                     // 32*512*256*4   = 16,777,216
  float*  xQws = (float*)(ws + 385875968);                     // 32*256*4       = 32,768
  int*    lastmap = (int*)(ws + 385908736);                    // 32*2048*4      = 262,144
  float*  hvmg = (float*)(ws + 386170880);                     // 32*2048*4      = 262,144
  float*  wgtg = (float*)(ws + 386433024);                     // 32*512*4       = 65,536
  (void)ws_size; (void)in_sizes; (void)n_in; (void)out_size;

  // 1) xK (fp64) = ctx @ W_K^T : per batch M=512,N=256,K=1024
  gemm_abt<float, float, double><<<dim3(KK / 64, TT / 64, BB), 256, 0, stream>>>(
      x, (long long)SFULL * DD, DD,
      W_K, 0LL, DD,
      xK64, (long long)TT * KK, KK, DD);

  // 2) xV (fp32) = ctx @ W_V^T
  gemm_abt<float, float, float><<<dim3(VV / 64, TT / 64, BB), 256, 0, stream>>>(
      x, (long long)SFULL * DD, DD,
      W_V, 0LL, DD,
      xVws, (long long)TT * VV, VV, DD);

  // 3) xQ
  xq_kernel<<<BB, 256, 0, stream>>>(x, W_Q, xQws, outp);

  // 4) L0t[b,t,h] = <xK[b,t], W_hi0[b,h]>  : M=512, N=2048, K=256
  gemm_abt<double, float, double><<<dim3(HH / 64, TT / 64, BB), 256, 0, stream>>>(
      xK64, (long long)TT * KK, KK,
      W_hi0, (long long)HH * KK, KK,
      L0t, (long long)TT * HH, HH, KK);

  // 5) Gram[b,t,s] = <xK[b,t], xK[b,s]> : M=N=512, K=256
  gemm_abt<double, double, double><<<dim3(TT / 64, TT / 64, BB), 256, 0, stream>>>(
      xK64, (long long)TT * KK, KK,
      xK64, (long long)TT * KK, KK,
      Gram, (long long)TT * TT, TT, KK);

  // 6) sequential winner scan
  scan_kernel<<<BB, 1024, 0, stream>>>(L0t, Gram, lastmap);

  // 7) q-logits + softmax -> hvm, wgt
  epi1_kernel<<<BB, 1024, 0, stream>>>(W_hi0, xK64, xQws, lastmap, hvmg, wgtg);

  // 8) reinst_context
  epi2_kernel<<<dim3(DD / 256, BB), 256, 0, stream>>>(W_reinst0, x, hvmg, wgtg, outp);

  // 9) mhn_out + projection
  epi3_kernel<<<BB, 1024, 0, stream>>>(W_oh0, xVws, W_proj, hvmg, wgtg, outp);
}